// Round 3
// baseline (1066.279 us; speedup 1.0000x reference)
//
#include <hip/hip_runtime.h>
#include <math.h>

typedef float f2 __attribute__((ext_vector_type(2)));

// Problem constants
#define BN 32
#define CC 8
#define HH 300
#define WW 300
#define HW 90000
#define NPX (BN * HW)

// Tiling for fused kernel
#define TH 20
#define TW 20
#define NTY 15
#define NTX 15

// Workspace layout (float offsets)
#define OFF_P5   0              // [32][8][60*60]
#define OFF_P10  921600         // [32][8][30*30]
#define OFF_P15  1152000        // [32][8][20*20]
#define OFF_WA   1254400        // [3][16][8][9]
#define OFF_GWA  1257856        // [24][8][9]
#define OFF_MWA  1259584        // [24][8][9]
#define STAT_BYTE_OFF  5045248  // [16][64] doubles
#define SS_BYTE_OFF    5053440  // 16 floats

// ---------------------------------------------------------------------------
__global__ void k_setup(const float* __restrict__ w5, const float* __restrict__ w10,
                        const float* __restrict__ w15, const float* __restrict__ gw,
                        const float* __restrict__ mw, float* __restrict__ ws,
                        double* __restrict__ stats) {
    int t = threadIdx.x;
    for (int idx = t; idx < 3 * 16 * 8 * 9; idx += 256) {
        int kk = idx / 1152;
        int rem = idx % 1152;
        int ci = rem / 72;
        int r2 = rem % 72;
        int o = r2 / 9;
        int tap = r2 % 9;
        const float* src = (kk == 0) ? w5 : ((kk == 1) ? w10 : w15);
        ws[OFF_WA + idx] = src[(o * 16 + ci) * 9 + tap];
    }
    for (int idx = t; idx < 24 * 72; idx += 256) {
        int kc = idx / 72;
        int r2 = idx % 72;
        int o = r2 / 9;
        int tap = r2 % 9;
        ws[OFF_GWA + idx] = gw[(o * 24 + kc) * 9 + tap];
        ws[OFF_MWA + idx] = mw[(o * 24 + kc) * 9 + tap];
    }
    for (int idx = t; idx < 16 * 64; idx += 256) stats[idx] = 0.0;
}

// ---------------------------------------------------------------------------
__global__ void k_pool(const float* __restrict__ x, float* __restrict__ ws) {
    int bc = blockIdx.x;
    const float* xp = x + (size_t)bc * HW;
    __shared__ float p5[3600];

    for (int cell = threadIdx.x; cell < 3600; cell += 256) {
        int pi = cell / 60, pj = cell % 60;
        const float* rp = xp + pi * 5 * WW + pj * 5;
        float s = 0.f;
#pragma unroll
        for (int u = 0; u < 5; u++)
#pragma unroll
            for (int v = 0; v < 5; v++) s += rp[u * WW + v];
        float m = s * 0.04f;
        p5[cell] = m;
        ws[OFF_P5 + bc * 3600 + cell] = m;
    }
    __syncthreads();
    for (int cell = threadIdx.x; cell < 900; cell += 256) {
        int pi = cell / 30, pj = cell % 30;
        float s = p5[(2 * pi) * 60 + 2 * pj] + p5[(2 * pi) * 60 + 2 * pj + 1] +
                  p5[(2 * pi + 1) * 60 + 2 * pj] + p5[(2 * pi + 1) * 60 + 2 * pj + 1];
        ws[OFF_P10 + bc * 900 + cell] = s * 0.25f;
    }
    for (int cell = threadIdx.x; cell < 400; cell += 256) {
        int pi = cell / 20, pj = cell % 20;
        float s = 0.f;
#pragma unroll
        for (int u = 0; u < 3; u++)
#pragma unroll
            for (int v = 0; v < 3; v++) s += p5[(3 * pi + u) * 60 + 3 * pj + v];
        ws[OFF_P15 + bc * 400 + cell] = s * (1.f / 9.f);
    }
}

// ---------------------------------------------------------------------------
// per-scale body; packed-fp32 (v_pk_fma_f32) formulation: each thread owns a
// horizontal pixel pair -> float2 accumulators, tap dc consumes pair
// (v[dc], v[dc+1]). Aligned pairs via 8B LDS loads; middle pair via 2 movs.
// ---------------------------------------------------------------------------
template <int K, int PW, int NC>
__device__ __forceinline__ void do_kk(
    float xs[8][24][26], float cs[8][22][24], float pc[8][36],
    const float* __restrict__ pooled, const float* __restrict__ bias,
    const float* __restrict__ wk,   // [16][8][9]
    const float* __restrict__ gwk,  // [8][8][9]
    const float* __restrict__ mwk,
    int b, int r0, int c0, int t, int cp_i, int cp_j, int p_i, int p_j,
    f2* gA, f2* mA) {
    const int cr0 = (int)((unsigned)(r0 - 2 + 60) / K) - 60 / K;
    const int cc0 = (int)((unsigned)(c0 - 2 + 60) / K) - 60 / K;

    __syncthreads();  // prev phases done with pc/cs
    for (int idx = t; idx < 8 * NC * NC; idx += 256) {
        int ch = idx / (NC * NC), rem = idx % (NC * NC);
        int i = rem / NC, j = rem % NC;
        int pi = cr0 + i, pj = cc0 + j;
        float v = 0.f;
        if (pi >= 0 && pi < PW && pj >= 0 && pj < PW)
            v = pooled[(size_t)(b * 8 + ch) * (PW * PW) + pi * PW + pj];
        pc[ch][rem] = v;
    }
    __syncthreads();

    // c-phase: conv([x, up_k]) -> cs (22x22, packed pixel pair / thread)
    if (t < 242) {
        const int r = r0 - 1 + cp_i;
        const int c = c0 - 1 + cp_j;
        f2 acc[8];
#pragma unroll
        for (int o = 0; o < 8; o++) acc[o] = (f2)(0.f);

        // x channels 0..7
        for (int ci = 0; ci < 8; ci++) {
            const float* wu = wk + ci * 72;  // wave-uniform -> SGPR
            f2 pr[3][3];
#pragma unroll
            for (int dr = 0; dr < 3; dr++) {
                f2 pA = *(const f2*)&xs[ci][cp_i + dr][cp_j];
                f2 pC = *(const f2*)&xs[ci][cp_i + dr][cp_j + 2];
                f2 pM;
                pM.x = pA.y;
                pM.y = pC.x;
                pr[dr][0] = pA;
                pr[dr][1] = pM;
                pr[dr][2] = pC;
            }
#pragma unroll
            for (int o = 0; o < 8; o++)
#pragma unroll
                for (int dr = 0; dr < 3; dr++)
#pragma unroll
                    for (int dc = 0; dc < 3; dc++)
                        acc[o] += pr[dr][dc] * wu[o * 9 + dr * 3 + dc];
        }
        // up channels 8..15 from pooled cells
        int roff[3], coff[4];
#pragma unroll
        for (int dr = 0; dr < 3; dr++)
            roff[dr] = ((int)((unsigned)(r - 1 + dr + 60) / K) - 60 / K - cr0) * NC;
#pragma unroll
        for (int dc = 0; dc < 4; dc++)
            coff[dc] = (int)((unsigned)(c - 1 + dc + 60) / K) - 60 / K - cc0;
        for (int ci = 0; ci < 8; ci++) {
            const float* wu = wk + (8 + ci) * 72;
            f2 pr[3][3];
#pragma unroll
            for (int dr = 0; dr < 3; dr++) {
                const float* pb = &pc[ci][roff[dr]];
#pragma unroll
                for (int dc = 0; dc < 3; dc++) {
                    f2 p;
                    p.x = pb[coff[dc]];
                    p.y = pb[coff[dc + 1]];
                    pr[dr][dc] = p;
                }
            }
#pragma unroll
            for (int o = 0; o < 8; o++)
#pragma unroll
                for (int dr = 0; dr < 3; dr++)
#pragma unroll
                    for (int dc = 0; dc < 3; dc++)
                        acc[o] += pr[dr][dc] * wu[o * 9 + dr * 3 + dc];
        }
        bool rok = (r >= 0 && r < HH);
        bool c0ok = rok && (c >= 0 && c < WW);
        bool c1ok = rok && (c + 1 >= 0 && c + 1 < WW);
#pragma unroll
        for (int o = 0; o < 8; o++) {
            float bo = bias[o];
            cs[o][cp_i][cp_j] = c0ok ? (acc[o].x + bo) : 0.f;
            cs[o][cp_i][cp_j + 1] = c1ok ? (acc[o].y + bo) : 0.f;
        }
    }
    __syncthreads();

    // gate-phase: accumulate this scale's 8 g_in channels into G/M packed accums
    if (t < 200) {
        for (int ci = 0; ci < 8; ci++) {
            const float* gu = gwk + ci * 72;
            const float* mu = mwk + ci * 72;
            f2 pr[3][3];
#pragma unroll
            for (int dr = 0; dr < 3; dr++) {
                f2 pA = *(const f2*)&cs[ci][p_i + dr][p_j];
                f2 pC = *(const f2*)&cs[ci][p_i + dr][p_j + 2];
                f2 pM;
                pM.x = pA.y;
                pM.y = pC.x;
                pr[dr][0] = pA;
                pr[dr][1] = pM;
                pr[dr][2] = pC;
            }
#pragma unroll
            for (int o = 0; o < 8; o++)
#pragma unroll
                for (int dr = 0; dr < 3; dr++)
#pragma unroll
                    for (int dc = 0; dc < 3; dc++) {
                        gA[o] += pr[dr][dc] * gu[o * 9 + dr * 3 + dc];
                        mA[o] += pr[dr][dc] * mu[o * 9 + dr * 3 + dc];
                    }
        }
    }
}

// ---------------------------------------------------------------------------
__global__ __launch_bounds__(256, 4) void k_fused(
    const float* __restrict__ x, const float* __restrict__ ws,
    const float* __restrict__ b5, const float* __restrict__ b10, const float* __restrict__ b15,
    const float* __restrict__ gb, const float* __restrict__ mb,
    float* __restrict__ out, double* __restrict__ stats) {
    __shared__ float xs[8][24][26];  // x halo2, even stride (8B-aligned pairs)
    __shared__ float cs[8][22][24];  // c_k tile halo1, even stride
    __shared__ float pc[8][36];
    __shared__ float red[4][16];

    const int bx = blockIdx.x, by = blockIdx.y, b = blockIdx.z;
    const int r0 = by * TH, c0 = bx * TW;
    const int t = threadIdx.x;

    const float* xb = x + (size_t)b * CC * HW;

    for (int idx = t; idx < 8 * 576; idx += 256) {
        int ch = idx / 576, rem = idx % 576, i = rem / 24, j = rem % 24;
        int r = r0 - 2 + i, c = c0 - 2 + j;
        float v = 0.f;
        if (r >= 0 && r < HH && c >= 0 && c < WW) v = xb[ch * HW + r * WW + c];
        xs[ch][i][j] = v;
    }

    f2 gA[8], mA[8];
#pragma unroll
    for (int o = 0; o < 8; o++) { gA[o] = (f2)(0.f); mA[o] = (f2)(0.f); }

    const float* wA = ws + OFF_WA;
    const float* gwA = ws + OFF_GWA;
    const float* mwA = ws + OFF_MWA;

    const int cp_i = t / 11, cp_j = 2 * (t % 11);
    const int p_i = t / 10, p_j = 2 * (t % 10);

    do_kk<5, 60, 6>(xs, cs, pc, ws + OFF_P5, b5, wA, gwA, mwA,
                    b, r0, c0, t, cp_i, cp_j, p_i, p_j, gA, mA);
    do_kk<10, 30, 4>(xs, cs, pc, ws + OFF_P10, b10, wA + 1152, gwA + 576, mwA + 576,
                     b, r0, c0, t, cp_i, cp_j, p_i, p_j, gA, mA);
    do_kk<15, 20, 3>(xs, cs, pc, ws + OFF_P15, b15, wA + 2304, gwA + 1152, mwA + 1152,
                     b, r0, c0, t, cp_i, cp_j, p_i, p_j, gA, mA);

    float ls[8], ls2[8];
#pragma unroll
    for (int o = 0; o < 8; o++) { ls[o] = 0.f; ls2[o] = 0.f; }
    if (t < 200) {
        int r = r0 + p_i, c = c0 + p_j;
#pragma unroll
        for (int o = 0; o < 8; o++) {
            float gbo = gb[o], mbo = mb[o];
            float g0 = gA[o].x + gbo, m0 = mA[o].x + mbo;
            float g1 = gA[o].y + gbo, m1 = mA[o].y + mbo;
            float y0 = g0 / (1.f + expf(-m0));
            float y1 = g1 / (1.f + expf(-m1));
            size_t base = (size_t)(b * 8 + o) * HW + r * WW + c;
            out[base] = y0;
            out[base + 1] = y1;
            ls[o] = y0 + y1;
            ls2[o] = y0 * y0 + y1 * y1;
        }
    }
#pragma unroll
    for (int o = 0; o < 8; o++) {
        float s1 = ls[o], s2 = ls2[o];
#pragma unroll
        for (int off = 32; off > 0; off >>= 1) {
            s1 += __shfl_down(s1, off);
            s2 += __shfl_down(s2, off);
        }
        if ((t & 63) == 0) {
            red[t >> 6][o] = s1;
            red[t >> 6][8 + o] = s2;
        }
    }
    __syncthreads();
    if (t < 16) {
        float s = red[0][t] + red[1][t] + red[2][t] + red[3][t];
        int hash = (blockIdx.x + 15 * blockIdx.y + 225 * blockIdx.z) & 63;
        atomicAdd(&stats[t * 64 + hash], (double)s);
    }
}

// ---------------------------------------------------------------------------
__global__ void k_stats(const double* __restrict__ stats, const float* __restrict__ gamma,
                        const float* __restrict__ beta, float* __restrict__ ss) {
    __shared__ double tot[16];
    int t = threadIdx.x;
    if (t < 16) {
        double s = 0.0;
        for (int i = 0; i < 64; i++) s += stats[t * 64 + i];
        tot[t] = s;
    }
    __syncthreads();
    if (t < 8) {
        double N = (double)NPX;
        double mean = tot[t] / N;
        double var = tot[8 + t] / N - mean * mean;
        double scale = (double)gamma[t] / sqrt(var + 1e-5);
        ss[t] = (float)scale;
        ss[8 + t] = (float)((double)beta[t] - mean * scale);
    }
}

// ---------------------------------------------------------------------------
__global__ void k_norm(float* __restrict__ out, const float* __restrict__ ss) {
    int i = blockIdx.x * 256 + threadIdx.x;
    if (i < (BN * CC * HW) / 4) {
        int plane = (i * 4) / HW;
        int ch = plane & 7;
        float sc = ss[ch], sh = ss[8 + ch];
        float4* p = (float4*)out + i;
        float4 v = *p;
        v.x = v.x * sc + sh;
        v.y = v.y * sc + sh;
        v.z = v.z * sc + sh;
        v.w = v.w * sc + sh;
        *p = v;
    }
}

// ---------------------------------------------------------------------------
extern "C" void kernel_launch(void* const* d_in, const int* in_sizes, int n_in,
                              void* d_out, int out_size, void* d_ws, size_t ws_size,
                              hipStream_t stream) {
    const float* x = (const float*)d_in[0];
    const float* w5 = (const float*)d_in[1];
    const float* b5 = (const float*)d_in[2];
    const float* w10 = (const float*)d_in[3];
    const float* b10 = (const float*)d_in[4];
    const float* w15 = (const float*)d_in[5];
    const float* b15 = (const float*)d_in[6];
    const float* gw = (const float*)d_in[7];
    const float* gb = (const float*)d_in[8];
    const float* mw = (const float*)d_in[9];
    const float* mb = (const float*)d_in[10];
    const float* gamma = (const float*)d_in[11];
    const float* beta = (const float*)d_in[12];

    float* out = (float*)d_out;
    float* ws = (float*)d_ws;
    double* stats = (double*)((char*)d_ws + STAT_BYTE_OFF);
    float* ss = (float*)((char*)d_ws + SS_BYTE_OFF);

    k_setup<<<1, 256, 0, stream>>>(w5, w10, w15, gw, mw, ws, stats);
    k_pool<<<BN * CC, 256, 0, stream>>>(x, ws);
    dim3 grid(NTX, NTY, BN);
    k_fused<<<grid, 256, 0, stream>>>(x, ws, b5, b10, b15, gb, mb, out, stats);
    k_stats<<<1, 64, 0, stream>>>(stats, gamma, beta, ss);
    k_norm<<<(BN * CC * HW / 4 + 255) / 256, 256, 0, stream>>>(out, ss);
}

// Round 5
// 573.385 us; speedup vs baseline: 1.8596x; 1.8596x over previous
//
#include <hip/hip_runtime.h>
#include <math.h>

typedef __bf16 bfrag __attribute__((ext_vector_type(8)));
typedef float f32x4 __attribute__((ext_vector_type(4)));

// Problem constants
#define BN 32
#define HH 300
#define WW 300
#define HW 90000
#define NPX (BN * HW)

// Output tile 16 rows x 32 cols
#define GX 10   // ceil(300/32)
#define GY 19   // ceil(300/16)

// Workspace layout
#define OFF_P5   0              // [32][8][60*60] fp32
#define OFF_P10  921600
#define OFF_P15  1152000
#define CWB_BYTE_OFF  5017600   // [3][16][10][16] bf16 = 15360 B
#define GWB_BYTE_OFF  5032960   // [16][28][8] bf16 = 7168 B
#define STAT_BYTE_OFF 5040128   // [16][64] doubles
#define SS_BYTE_OFF   5048320   // 16 floats

__device__ __forceinline__ short f2bf(float f) {
    union { float f; unsigned u; } v;
    v.f = f;
    unsigned r = v.u + 0x7FFF + ((v.u >> 16) & 1);
    return (short)(r >> 16);
}

// ---------------------------------------------------------------------------
// K0: build bf16 MFMA weight layouts + zero BN stat bins
// cB[s][n16][tap10][ci16]  (n>=8, tap==9 -> 0);  gB[n16][blk28][cj8] (blk>=27 -> 0)
// ---------------------------------------------------------------------------
__global__ void k_setup(const float* __restrict__ w5, const float* __restrict__ w10,
                        const float* __restrict__ w15, const float* __restrict__ gw,
                        const float* __restrict__ mw, short* __restrict__ cBg,
                        short* __restrict__ gBg, double* __restrict__ stats) {
    int t = threadIdx.x;
    for (int idx = t; idx < 7680; idx += 256) {
        int s = idx / 2560, rem = idx % 2560;
        int n = rem / 160, r2 = rem % 160;
        int tap = r2 / 16, ci = r2 % 16;
        float v = 0.f;
        if (n < 8 && tap < 9) {
            const float* W = (s == 0) ? w5 : ((s == 1) ? w10 : w15);
            v = W[(n * 16 + ci) * 9 + tap];
        }
        cBg[idx] = f2bf(v);
    }
    for (int idx = t; idx < 3584; idx += 256) {
        int n = idx / 224, r2 = idx % 224;
        int blk = r2 / 8, cj = r2 % 8;
        float v = 0.f;
        if (blk < 27) {
            int tap = blk / 3, ci24 = (blk % 3) * 8 + cj;
            if (n < 8) v = gw[(n * 24 + ci24) * 9 + tap];
            else       v = mw[((n - 8) * 24 + ci24) * 9 + tap];
        }
        gBg[idx] = f2bf(v);
    }
    for (int idx = t; idx < 16 * 64; idx += 256) stats[idx] = 0.0;
}

// ---------------------------------------------------------------------------
// K1: adaptive-avg-pool to 60x60 (k=5), derive 30x30, 20x20 (fp32 planes)
// ---------------------------------------------------------------------------
__global__ void k_pool(const float* __restrict__ x, float* __restrict__ ws) {
    int bc = blockIdx.x;
    const float* xp = x + (size_t)bc * HW;
    __shared__ float p5[3600];

    for (int cell = threadIdx.x; cell < 3600; cell += 256) {
        int pi = cell / 60, pj = cell % 60;
        const float* rp = xp + pi * 5 * WW + pj * 5;
        float s = 0.f;
#pragma unroll
        for (int u = 0; u < 5; u++)
#pragma unroll
            for (int v = 0; v < 5; v++) s += rp[u * WW + v];
        float m = s * 0.04f;
        p5[cell] = m;
        ws[OFF_P5 + bc * 3600 + cell] = m;
    }
    __syncthreads();
    for (int cell = threadIdx.x; cell < 900; cell += 256) {
        int pi = cell / 30, pj = cell % 30;
        float s = p5[(2 * pi) * 60 + 2 * pj] + p5[(2 * pi) * 60 + 2 * pj + 1] +
                  p5[(2 * pi + 1) * 60 + 2 * pj] + p5[(2 * pi + 1) * 60 + 2 * pj + 1];
        ws[OFF_P10 + bc * 900 + cell] = s * 0.25f;
    }
    for (int cell = threadIdx.x; cell < 400; cell += 256) {
        int pi = cell / 20, pj = cell % 20;
        float s = 0.f;
#pragma unroll
        for (int u = 0; u < 3; u++)
#pragma unroll
            for (int v = 0; v < 3; v++) s += p5[(3 * pi + u) * 60 + 3 * pj + v];
        ws[OFF_P15 + bc * 400 + cell] = s * (1.f / 9.f);
    }
}

// ---------------------------------------------------------------------------
template <int K, int PW, int NR, int NCC>
__device__ __forceinline__ void stage_pc(const float* __restrict__ pooled, float* pc,
                                         int b, int r0, int c0, int t) {
    const int cr0 = (int)((unsigned)(r0 - 2 + 60) / K) - 60 / K;
    const int cc0 = (int)((unsigned)(c0 - 2 + 60) / K) - 60 / K;
    for (int idx = t; idx < 8 * NR * NCC; idx += 256) {
        int ch = idx / (NR * NCC), rem = idx % (NR * NCC);
        int i = rem / NCC, j = rem % NCC;
        int pi = cr0 + i, pj = cc0 + j;
        float v = 0.f;
        if (pi >= 0 && pi < PW && pj >= 0 && pj < PW)
            v = pooled[((size_t)(b * 8 + ch) * PW + pi) * PW + pj];
        pc[ch * 45 + rem] = v;
    }
}

template <int K, int NCC>
__device__ __forceinline__ void stage_up(short* xu, const float* pc,
                                         int b, int r0, int c0, int t) {
    const int cr0 = (int)((unsigned)(r0 - 2 + 60) / K) - 60 / K;
    const int cc0 = (int)((unsigned)(c0 - 2 + 60) / K) - 60 / K;
    for (int idx = t; idx < 2880; idx += 256) {
        int cp = idx / 720, rem = idx % 720;
        int i = rem / 36, j = rem % 36;
        int ra = r0 - 2 + i, ca = c0 - 2 + j;
        bool ok = (ra >= 0 && ra < HH && ca >= 0 && ca < WW);
        int ci = (int)((unsigned)(ra + 60) / K) - 60 / K - cr0;
        int cj = (int)((unsigned)(ca + 60) / K) - 60 / K - cc0;
        int cell = ci * NCC + cj;
        float v0 = 0.f, v1 = 0.f;
        if (ok) {
            v0 = pc[(2 * cp) * 45 + cell];
            v1 = pc[(2 * cp + 1) * 45 + cell];
        }
        unsigned p = (unsigned short)f2bf(v0) | ((unsigned)(unsigned short)f2bf(v1) << 16);
        *(unsigned*)&xu[(i * 36 + j) * 16 + 8 + 2 * cp] = p;
    }
}

// c-phase: conv([x, up_s]) over the 18x34 c-tile via 39 M-groups x 5 K-MFMAs
// NOTE: weight index (tapw) is UNCLAMPED so the pad slot (tap 9) multiplies by
// genuine zeros; only the A-side address (tapa) is clamped as an OOB guard.
__device__ __forceinline__ void c_phase(const short* xu, short* cwS, const short* cBs,
                                        const float* __restrict__ bias, int s,
                                        int r0, int c0, int lane, int wid) {
    const int n = lane & 15, quad = lane >> 4;
    const int qh = quad >> 1, ql = quad & 1;
    bfrag bfr[5];
    int tapoff[5];
#pragma unroll
    for (int km = 0; km < 5; km++) {
        int tapw = km * 2 + qh;                 // weight index: 9 -> zero row in cB
        int tapa = (tapw > 8) ? 8 : tapw;       // address clamp only (finite data)
        bfr[km] = *(const bfrag*)&cBs[(n * 10 + tapw) * 16 + ql * 8];
        tapoff[km] = ((tapa / 3) * 36 + tapa % 3) * 16;
    }
    float bo = (n < 8) ? bias[n] : 0.f;
    for (int g = wid; g < 39; g += 4) {
        int px = g * 16 + n;
        if (px > 611) px = 611;
        int rp = px / 34, cp = px - rp * 34;
        int off0 = (rp * 36 + cp) * 16 + ql * 8;
        f32x4 acc = {0.f, 0.f, 0.f, 0.f};
#pragma unroll
        for (int km = 0; km < 5; km++)
            acc = __builtin_amdgcn_mfma_f32_16x16x32_bf16(
                *(const bfrag*)&xu[off0 + tapoff[km]], bfr[km], acc, 0, 0, 0);
        if (n < 8) {
#pragma unroll
            for (int reg = 0; reg < 4; reg++) {
                int px2 = g * 16 + quad * 4 + reg;
                if (px2 < 612) {
                    int r2 = px2 / 34, c2 = px2 - r2 * 34;
                    int ra = r0 - 1 + r2, ca = c0 - 1 + c2;
                    float v = acc[reg] + bo;
                    if (ra < 0 || ra >= HH || ca < 0 || ca >= WW) v = 0.f;
                    cwS[(r2 * 34 + c2) * 24 + s * 8 + n] = f2bf(v);
                }
            }
        }
    }
}

// ---------------------------------------------------------------------------
// K2: fused MFMA kernel — one 16x32 output tile per 256-thread block
// ---------------------------------------------------------------------------
__global__ __launch_bounds__(256, 2) void k_fused(
    const float* __restrict__ x, const float* __restrict__ wsf,
    const short* __restrict__ cBg, const short* __restrict__ gBg,
    const float* __restrict__ b5, const float* __restrict__ b10, const float* __restrict__ b15,
    const float* __restrict__ gb, const float* __restrict__ mb,
    float* __restrict__ out, double* __restrict__ stats) {
    __shared__ __align__(16) short xu[20 * 36 * 16];   // [i20][j36][ci16] bf16 (x:0-7, up:8-15)
    __shared__ __align__(16) short cwS[18 * 34 * 24];  // [r18][c34][ci24] bf16
    __shared__ __align__(16) short cB[7680];
    __shared__ __align__(16) short gB[3584];
    __shared__ float pc[8 * 45];

    const int b = blockIdx.z;
    const int r0 = blockIdx.y * 16, c0 = blockIdx.x * 32;
    const int t = threadIdx.x, lane = t & 63, wid = t >> 6;

    // phase 0: weights -> LDS, x half of xu, pooled cells for scale 0
    for (int i = t; i < 3840; i += 256) ((int*)cB)[i] = ((const int*)cBg)[i];
    for (int i = t; i < 1792; i += 256) ((int*)gB)[i] = ((const int*)gBg)[i];
    for (int idx = t; idx < 2880; idx += 256) {
        int cp = idx / 720, rem = idx % 720;
        int i = rem / 36, j = rem % 36;
        int ra = r0 - 2 + i, ca = c0 - 2 + j;
        float v0 = 0.f, v1 = 0.f;
        if (ra >= 0 && ra < HH && ca >= 0 && ca < WW) {
            size_t base = ((size_t)(b * 8 + 2 * cp) * HH + ra) * WW + ca;
            v0 = x[base];
            v1 = x[base + HW];
        }
        unsigned p = (unsigned short)f2bf(v0) | ((unsigned)(unsigned short)f2bf(v1) << 16);
        *(unsigned*)&xu[(i * 36 + j) * 16 + 2 * cp] = p;
    }
    stage_pc<5, 60, 5, 8>(wsf + OFF_P5, pc, b, r0, c0, t);
    __syncthreads();
    stage_up<5, 8>(xu, pc, b, r0, c0, t);
    __syncthreads();

    c_phase(xu, cwS, cB, b5, 0, r0, c0, lane, wid);
    stage_pc<10, 30, 3, 5>(wsf + OFF_P10, pc, b, r0, c0, t);
    __syncthreads();
    stage_up<10, 5>(xu, pc, b, r0, c0, t);
    __syncthreads();

    c_phase(xu, cwS, cB + 2560, b10, 1, r0, c0, lane, wid);
    stage_pc<15, 20, 3, 4>(wsf + OFF_P15, pc, b, r0, c0, t);
    __syncthreads();
    stage_up<15, 4>(xu, pc, b, r0, c0, t);
    __syncthreads();

    c_phase(xu, cwS, cB + 5120, b15, 2, r0, c0, lane, wid);
    __syncthreads();

    // gate phase: N=16 packs G(0-7) and M(8-15); 32 M-groups x 7 K-MFMAs
    // Same clamp discipline: blkw (weights, 27 -> zero block) vs blka (address).
    const int n = lane & 15, quad = lane >> 4;
    bfrag gfr[7];
    int goff[7];
#pragma unroll
    for (int km = 0; km < 7; km++) {
        int blkw = km * 4 + quad;               // weight index: 27 -> zero block in gB
        int blka = (blkw > 26) ? 26 : blkw;     // address clamp only
        gfr[km] = *(const bfrag*)&gB[(n * 28 + blkw) * 8];
        int tap = blka / 3, cig = blka - tap * 3;
        goff[km] = ((tap / 3) * 34 + tap % 3) * 24 + cig * 8;
    }
    float gbv = (n < 8) ? gb[n] : 0.f;
    float mbv = (n < 8) ? mb[n] : 0.f;
    float ls = 0.f, ls2 = 0.f;

    for (int g = wid; g < 32; g += 4) {
        int px = g * 16 + n;
        int rr = px >> 5, cc2 = px & 31;
        int off0 = (rr * 34 + cc2) * 24;
        f32x4 acc = {0.f, 0.f, 0.f, 0.f};
#pragma unroll
        for (int km = 0; km < 7; km++)
            acc = __builtin_amdgcn_mfma_f32_16x16x32_bf16(
                *(const bfrag*)&cwS[off0 + goff[km]], gfr[km], acc, 0, 0, 0);
#pragma unroll
        for (int reg = 0; reg < 4; reg++) {
            float other = __shfl_xor(acc[reg], 8);  // pair G (n<8) with M (n+8)
            if (n < 8) {
                int px2 = g * 16 + quad * 4 + reg;
                int rr2 = px2 >> 5, cc3 = px2 & 31;
                int ra = r0 + rr2, ca = c0 + cc3;
                if (ra < HH && ca < WW) {
                    float G = acc[reg] + gbv, M = other + mbv;
                    float y = G / (1.f + __expf(-M));
                    out[((size_t)(b * 8 + n) * HH + ra) * WW + ca] = y;
                    ls += y;
                    ls2 += y * y;
                }
            }
        }
    }
    // BN partials: sum quads via shfl_xor, then hashed-bin double atomics
    ls += __shfl_xor(ls, 16);
    ls += __shfl_xor(ls, 32);
    ls2 += __shfl_xor(ls2, 16);
    ls2 += __shfl_xor(ls2, 32);
    if (lane < 8) {
        int hash = (blockIdx.x + GX * blockIdx.y + GX * GY * blockIdx.z) & 63;
        atomicAdd(&stats[lane * 64 + hash], (double)ls);
        atomicAdd(&stats[(8 + lane) * 64 + hash], (double)ls2);
    }
}

// ---------------------------------------------------------------------------
__global__ void k_stats(const double* __restrict__ stats, const float* __restrict__ gamma,
                        const float* __restrict__ beta, float* __restrict__ ss) {
    __shared__ double tot[16];
    int t = threadIdx.x;
    if (t < 16) {
        double s = 0.0;
        for (int i = 0; i < 64; i++) s += stats[t * 64 + i];
        tot[t] = s;
    }
    __syncthreads();
    if (t < 8) {
        double N = (double)NPX;
        double mean = tot[t] / N;
        double var = tot[8 + t] / N - mean * mean;
        double scale = (double)gamma[t] / sqrt(var + 1e-5);
        ss[t] = (float)scale;
        ss[8 + t] = (float)((double)beta[t] - mean * scale);
    }
}

// ---------------------------------------------------------------------------
__global__ void k_norm(float* __restrict__ out, const float* __restrict__ ss) {
    int i = blockIdx.x * 256 + threadIdx.x;
    if (i < (BN * 8 * HW) / 4) {
        int plane = (i * 4) / HW;
        int ch = plane & 7;
        float sc = ss[ch], sh = ss[8 + ch];
        float4* p = (float4*)out + i;
        float4 v = *p;
        v.x = v.x * sc + sh;
        v.y = v.y * sc + sh;
        v.z = v.z * sc + sh;
        v.w = v.w * sc + sh;
        *p = v;
    }
}

// ---------------------------------------------------------------------------
extern "C" void kernel_launch(void* const* d_in, const int* in_sizes, int n_in,
                              void* d_out, int out_size, void* d_ws, size_t ws_size,
                              hipStream_t stream) {
    const float* x = (const float*)d_in[0];
    const float* w5 = (const float*)d_in[1];
    const float* b5 = (const float*)d_in[2];
    const float* w10 = (const float*)d_in[3];
    const float* b10 = (const float*)d_in[4];
    const float* w15 = (const float*)d_in[5];
    const float* b15 = (const float*)d_in[6];
    const float* gw = (const float*)d_in[7];
    const float* gb = (const float*)d_in[8];
    const float* mw = (const float*)d_in[9];
    const float* mb = (const float*)d_in[10];
    const float* gamma = (const float*)d_in[11];
    const float* beta = (const float*)d_in[12];

    float* out = (float*)d_out;
    float* wsf = (float*)d_ws;
    short* cBg = (short*)((char*)d_ws + CWB_BYTE_OFF);
    short* gBg = (short*)((char*)d_ws + GWB_BYTE_OFF);
    double* stats = (double*)((char*)d_ws + STAT_BYTE_OFF);
    float* ss = (float*)((char*)d_ws + SS_BYTE_OFF);

    k_setup<<<1, 256, 0, stream>>>(w5, w10, w15, gw, mw, cBg, gBg, stats);
    k_pool<<<BN * 8, 256, 0, stream>>>(x, wsf);
    dim3 grid(GX, GY, BN);
    k_fused<<<grid, 256, 0, stream>>>(x, wsf, cBg, gBg, b5, b10, b15, gb, mb, out, stats);
    k_stats<<<1, 64, 0, stream>>>(stats, gamma, beta, ss);
    k_norm<<<(BN * 8 * HW / 4 + 255) / 256, 256, 0, stream>>>(out, ss);
}

// Round 6
// 426.938 us; speedup vs baseline: 2.4975x; 1.3430x over previous
//
#include <hip/hip_runtime.h>
#include <math.h>

typedef __bf16 bfrag __attribute__((ext_vector_type(8)));
typedef float f32x4 __attribute__((ext_vector_type(4)));

// Problem constants
#define BN 32
#define HH 300
#define WW 300
#define HW 90000
#define NPX (BN * HW)

// Output tile 16 rows x 32 cols
#define GX 10   // ceil(300/32)
#define GY 19   // ceil(300/16)

// Workspace layout (bytes)
#define P5I_BYTE_OFF   0         // [32][3600][8] bf16 = 1,843,200
#define P10I_BYTE_OFF  1843200   // [32][900][8]  bf16 = 460,800
#define P15I_BYTE_OFF  2304000   // [32][400][8]  bf16 = 204,800
#define CWB_BYTE_OFF   2508800   // [3][16][10][16] bf16 = 15,360
#define GWB_BYTE_OFF   2524160   // [16][28][8] bf16 = 7,168
#define STAT_BYTE_OFF  2531328   // [16][64] doubles = 8,192
#define SS_BYTE_OFF    2539520   // 16 floats

__device__ __forceinline__ short f2bf(float f) {
    union { float f; unsigned u; } v;
    v.f = f;
    unsigned r = v.u + 0x7FFF + ((v.u >> 16) & 1);
    return (short)(r >> 16);
}

// ---------------------------------------------------------------------------
// K0: build bf16 MFMA weight layouts + zero BN stat bins
// cB[s][n16][tap10][ci16]  (n>=8, tap==9 -> 0);  gB[n16][blk28][cj8] (blk>=27 -> 0)
// ---------------------------------------------------------------------------
__global__ void k_setup(const float* __restrict__ w5, const float* __restrict__ w10,
                        const float* __restrict__ w15, const float* __restrict__ gw,
                        const float* __restrict__ mw, short* __restrict__ cBg,
                        short* __restrict__ gBg, double* __restrict__ stats) {
    int t = threadIdx.x;
    for (int idx = t; idx < 7680; idx += 256) {
        int s = idx / 2560, rem = idx % 2560;
        int n = rem / 160, r2 = rem % 160;
        int tap = r2 / 16, ci = r2 % 16;
        float v = 0.f;
        if (n < 8 && tap < 9) {
            const float* W = (s == 0) ? w5 : ((s == 1) ? w10 : w15);
            v = W[(n * 16 + ci) * 9 + tap];
        }
        cBg[idx] = f2bf(v);
    }
    for (int idx = t; idx < 3584; idx += 256) {
        int n = idx / 224, r2 = idx % 224;
        int blk = r2 / 8, cj = r2 % 8;
        float v = 0.f;
        if (blk < 27) {
            int tap = blk / 3, ci24 = (blk % 3) * 8 + cj;
            if (n < 8) v = gw[(n * 24 + ci24) * 9 + tap];
            else       v = mw[((n - 8) * 24 + ci24) * 9 + tap];
        }
        gBg[idx] = f2bf(v);
    }
    for (int idx = t; idx < 16 * 64; idx += 256) stats[idx] = 0.0;
}

// ---------------------------------------------------------------------------
// K1: adaptive-avg-pool; outputs are CHANNEL-INTERLEAVED bf16 planes
// p5i[b][cell3600][ch8], p10i[b][cell900][ch8], p15i[b][cell400][ch8]
// ---------------------------------------------------------------------------
__global__ void k_pool(const float* __restrict__ x, unsigned short* __restrict__ p5i,
                       unsigned short* __restrict__ p10i, unsigned short* __restrict__ p15i) {
    int bc = blockIdx.x;
    int b = bc >> 3, c = bc & 7;
    const float* xp = x + (size_t)bc * HW;
    __shared__ float p5[3600];

    for (int cell = threadIdx.x; cell < 3600; cell += 256) {
        int pi = cell / 60, pj = cell % 60;
        const float* rp = xp + pi * 5 * WW + pj * 5;
        float s = 0.f;
#pragma unroll
        for (int u = 0; u < 5; u++)
#pragma unroll
            for (int v = 0; v < 5; v++) s += rp[u * WW + v];
        float m = s * 0.04f;
        p5[cell] = m;
        p5i[((size_t)b * 3600 + cell) * 8 + c] = (unsigned short)f2bf(m);
    }
    __syncthreads();
    for (int cell = threadIdx.x; cell < 900; cell += 256) {
        int pi = cell / 30, pj = cell % 30;
        float s = p5[(2 * pi) * 60 + 2 * pj] + p5[(2 * pi) * 60 + 2 * pj + 1] +
                  p5[(2 * pi + 1) * 60 + 2 * pj] + p5[(2 * pi + 1) * 60 + 2 * pj + 1];
        p10i[((size_t)b * 900 + cell) * 8 + c] = (unsigned short)f2bf(s * 0.25f);
    }
    for (int cell = threadIdx.x; cell < 400; cell += 256) {
        int pi = cell / 20, pj = cell % 20;
        float s = 0.f;
#pragma unroll
        for (int u = 0; u < 3; u++)
#pragma unroll
            for (int v = 0; v < 3; v++) s += p5[(3 * pi + u) * 60 + 3 * pj + v];
        p15i[((size_t)b * 400 + cell) * 8 + c] = (unsigned short)f2bf(s * (1.f / 9.f));
    }
}

// ---------------------------------------------------------------------------
// up-channel staging, software-pipelined: global 16B load of interleaved
// pooled cell -> registers (issued before the barrier), LDS write after.
// ---------------------------------------------------------------------------
template <int K, int PW>
__device__ __forceinline__ void up_load(const unsigned short* __restrict__ pooled,
                                        int b, int r0, int c0, int t, uint4* v) {
#pragma unroll
    for (int it = 0; it < 3; it++) {
        int idx = t + 256 * it;
        uint4 val = {0u, 0u, 0u, 0u};
        if (idx < 720) {
            int i = idx / 36, j = idx - i * 36;
            int ra = r0 - 2 + i, ca = c0 - 2 + j;
            if (ra >= 0 && ra < HH && ca >= 0 && ca < WW) {
                int pi = (int)((unsigned)ra / K);
                int pj = (int)((unsigned)ca / K);
                val = *(const uint4*)&pooled[((size_t)b * (PW * PW) + pi * PW + pj) * 8];
            }
        }
        v[it] = val;
    }
}

__device__ __forceinline__ void up_store(short* xu, int t, const uint4* v) {
#pragma unroll
    for (int it = 0; it < 3; it++) {
        int idx = t + 256 * it;
        if (idx < 720) *(uint4*)&xu[idx * 16 + 8] = v[it];
    }
}

// ---------------------------------------------------------------------------
// c-phase: conv([x, up_s]) over the 18x34 c-tile via 39 M-groups x 5 K-MFMAs
// weight index (tapw) UNCLAMPED (pad slot multiplies genuine zeros); only the
// A-side address (tapa) is clamped as an OOB guard. B-fragments from global.
// ---------------------------------------------------------------------------
__device__ __forceinline__ void c_phase(const short* xu, short* cwS,
                                        const unsigned short* __restrict__ cBs,
                                        const float* __restrict__ bias, int s,
                                        int r0, int c0, int lane, int wid) {
    const int n = lane & 15, quad = lane >> 4;
    const int qh = quad >> 1, ql = quad & 1;
    bfrag bfr[5];
    int tapoff[5];
#pragma unroll
    for (int km = 0; km < 5; km++) {
        int tapw = km * 2 + qh;                 // 9 -> zero row in cB
        int tapa = (tapw > 8) ? 8 : tapw;       // address clamp only
        bfr[km] = *(const bfrag*)&cBs[(n * 10 + tapw) * 16 + ql * 8];
        tapoff[km] = ((tapa / 3) * 36 + tapa % 3) * 16;
    }
    float bo = (n < 8) ? bias[n] : 0.f;
    for (int g = wid; g < 39; g += 4) {
        int px = g * 16 + n;
        if (px > 611) px = 611;
        int rp = px / 34, cp = px - rp * 34;
        int off0 = (rp * 36 + cp) * 16 + ql * 8;
        f32x4 acc = {0.f, 0.f, 0.f, 0.f};
#pragma unroll
        for (int km = 0; km < 5; km++)
            acc = __builtin_amdgcn_mfma_f32_16x16x32_bf16(
                *(const bfrag*)&xu[off0 + tapoff[km]], bfr[km], acc, 0, 0, 0);
        if (n < 8) {
#pragma unroll
            for (int reg = 0; reg < 4; reg++) {
                int px2 = g * 16 + quad * 4 + reg;
                if (px2 < 612) {
                    int r2 = px2 / 34, c2 = px2 - r2 * 34;
                    int ra = r0 - 1 + r2, ca = c0 - 1 + c2;
                    float v = acc[reg] + bo;
                    if (ra < 0 || ra >= HH || ca < 0 || ca >= WW) v = 0.f;
                    cwS[(r2 * 34 + c2) * 24 + s * 8 + n] = f2bf(v);
                }
            }
        }
    }
}

// ---------------------------------------------------------------------------
// K2: fused MFMA kernel — one 16x32 output tile per 256-thread block
// LDS = xu(23040B) + cwS(29376B) = 52.4KB -> 3 blocks/CU
// ---------------------------------------------------------------------------
__global__ __launch_bounds__(256, 3) void k_fused(
    const float* __restrict__ x,
    const unsigned short* __restrict__ p5i, const unsigned short* __restrict__ p10i,
    const unsigned short* __restrict__ p15i,
    const unsigned short* __restrict__ cBg, const unsigned short* __restrict__ gBg,
    const float* __restrict__ b5, const float* __restrict__ b10, const float* __restrict__ b15,
    const float* __restrict__ gb, const float* __restrict__ mb,
    float* __restrict__ out, double* __restrict__ stats) {
    __shared__ __align__(16) short xu[20 * 36 * 16];   // [i20][j36][ci16] (x:0-7, up:8-15)
    __shared__ __align__(16) short cwS[18 * 34 * 24];  // [r18][c34][ci24]

    const int b = blockIdx.z;
    const int r0 = blockIdx.y * 16, c0 = blockIdx.x * 32;
    const int t = threadIdx.x, lane = t & 63, wid = t >> 6;

    // pipeline scale-0 pooled loads early (global->reg, no LDS dep)
    uint4 upv[3];
    up_load<5, 60>(p5i, b, r0, c0, t, upv);

    // x half of xu (bf16 pair packs)
    for (int idx = t; idx < 2880; idx += 256) {
        int cp = idx / 720, rem = idx % 720;
        int i = rem / 36, j = rem % 36;
        int ra = r0 - 2 + i, ca = c0 - 2 + j;
        float v0 = 0.f, v1 = 0.f;
        if (ra >= 0 && ra < HH && ca >= 0 && ca < WW) {
            size_t base = ((size_t)(b * 8 + 2 * cp) * HH + ra) * WW + ca;
            v0 = x[base];
            v1 = x[base + HW];
        }
        unsigned p = (unsigned short)f2bf(v0) | ((unsigned)(unsigned short)f2bf(v1) << 16);
        *(unsigned*)&xu[(i * 36 + j) * 16 + 2 * cp] = p;
    }
    up_store(xu, t, upv);
    __syncthreads();

    c_phase(xu, cwS, cBg, b5, 0, r0, c0, lane, wid);
    up_load<10, 30>(p10i, b, r0, c0, t, upv);   // overlaps c_phase compute
    __syncthreads();
    up_store(xu, t, upv);
    __syncthreads();

    c_phase(xu, cwS, cBg + 2560, b10, 1, r0, c0, lane, wid);
    up_load<15, 20>(p15i, b, r0, c0, t, upv);
    __syncthreads();
    up_store(xu, t, upv);
    __syncthreads();

    c_phase(xu, cwS, cBg + 5120, b15, 2, r0, c0, lane, wid);
    __syncthreads();

    // gate phase: N=16 packs G(0-7) and M(8-15); 32 M-groups x 7 K-MFMAs
    const int n = lane & 15, quad = lane >> 4;
    bfrag gfr[7];
    int goff[7];
#pragma unroll
    for (int km = 0; km < 7; km++) {
        int blkw = km * 4 + quad;               // 27 -> zero block in gB
        int blka = (blkw > 26) ? 26 : blkw;     // address clamp only
        gfr[km] = *(const bfrag*)&gBg[(n * 28 + blkw) * 8];
        int tap = blka / 3, cig = blka - tap * 3;
        goff[km] = ((tap / 3) * 34 + tap % 3) * 24 + cig * 8;
    }
    float gbv = (n < 8) ? gb[n] : 0.f;
    float mbv = (n < 8) ? mb[n] : 0.f;
    float ls = 0.f, ls2 = 0.f;

    for (int g = wid; g < 32; g += 4) {
        int px = g * 16 + n;
        int rr = px >> 5, cc2 = px & 31;
        int off0 = (rr * 34 + cc2) * 24;
        f32x4 acc = {0.f, 0.f, 0.f, 0.f};
#pragma unroll
        for (int km = 0; km < 7; km++)
            acc = __builtin_amdgcn_mfma_f32_16x16x32_bf16(
                *(const bfrag*)&cwS[off0 + goff[km]], gfr[km], acc, 0, 0, 0);
#pragma unroll
        for (int reg = 0; reg < 4; reg++) {
            float other = __shfl_xor(acc[reg], 8);  // pair G (n<8) with M (n+8)
            if (n < 8) {
                int px2 = g * 16 + quad * 4 + reg;
                int rr2 = px2 >> 5, cc3 = px2 & 31;
                int ra = r0 + rr2, ca = c0 + cc3;
                if (ra < HH && ca < WW) {
                    float G = acc[reg] + gbv, M = other + mbv;
                    float y = G / (1.f + __expf(-M));
                    out[((size_t)(b * 8 + n) * HH + ra) * WW + ca] = y;
                    ls += y;
                    ls2 += y * y;
                }
            }
        }
    }
    // BN partials: quad-fold via shfl_xor, then hashed-bin double atomics
    ls += __shfl_xor(ls, 16);
    ls += __shfl_xor(ls, 32);
    ls2 += __shfl_xor(ls2, 16);
    ls2 += __shfl_xor(ls2, 32);
    if (lane < 8) {
        int hash = (blockIdx.x + GX * blockIdx.y + GX * GY * blockIdx.z) & 63;
        atomicAdd(&stats[lane * 64 + hash], (double)ls);
        atomicAdd(&stats[(8 + lane) * 64 + hash], (double)ls2);
    }
}

// ---------------------------------------------------------------------------
__global__ void k_stats(const double* __restrict__ stats, const float* __restrict__ gamma,
                        const float* __restrict__ beta, float* __restrict__ ss) {
    __shared__ double tot[16];
    int t = threadIdx.x;
    if (t < 16) {
        double s = 0.0;
        for (int i = 0; i < 64; i++) s += stats[t * 64 + i];
        tot[t] = s;
    }
    __syncthreads();
    if (t < 8) {
        double N = (double)NPX;
        double mean = tot[t] / N;
        double var = tot[8 + t] / N - mean * mean;
        double scale = (double)gamma[t] / sqrt(var + 1e-5);
        ss[t] = (float)scale;
        ss[8 + t] = (float)((double)beta[t] - mean * scale);
    }
}

// ---------------------------------------------------------------------------
__global__ void k_norm(float* __restrict__ out, const float* __restrict__ ss) {
    int i = blockIdx.x * 256 + threadIdx.x;
    if (i < (BN * 8 * HW) / 4) {
        int plane = (i * 4) / HW;
        int ch = plane & 7;
        float sc = ss[ch], sh = ss[8 + ch];
        float4* p = (float4*)out + i;
        float4 v = *p;
        v.x = v.x * sc + sh;
        v.y = v.y * sc + sh;
        v.z = v.z * sc + sh;
        v.w = v.w * sc + sh;
        *p = v;
    }
}

// ---------------------------------------------------------------------------
extern "C" void kernel_launch(void* const* d_in, const int* in_sizes, int n_in,
                              void* d_out, int out_size, void* d_ws, size_t ws_size,
                              hipStream_t stream) {
    const float* x = (const float*)d_in[0];
    const float* w5 = (const float*)d_in[1];
    const float* b5 = (const float*)d_in[2];
    const float* w10 = (const float*)d_in[3];
    const float* b10 = (const float*)d_in[4];
    const float* w15 = (const float*)d_in[5];
    const float* b15 = (const float*)d_in[6];
    const float* gw = (const float*)d_in[7];
    const float* gb = (const float*)d_in[8];
    const float* mw = (const float*)d_in[9];
    const float* mb = (const float*)d_in[10];
    const float* gamma = (const float*)d_in[11];
    const float* beta = (const float*)d_in[12];

    float* out = (float*)d_out;
    unsigned short* p5i = (unsigned short*)((char*)d_ws + P5I_BYTE_OFF);
    unsigned short* p10i = (unsigned short*)((char*)d_ws + P10I_BYTE_OFF);
    unsigned short* p15i = (unsigned short*)((char*)d_ws + P15I_BYTE_OFF);
    short* cBg = (short*)((char*)d_ws + CWB_BYTE_OFF);
    short* gBg = (short*)((char*)d_ws + GWB_BYTE_OFF);
    double* stats = (double*)((char*)d_ws + STAT_BYTE_OFF);
    float* ss = (float*)((char*)d_ws + SS_BYTE_OFF);

    k_setup<<<1, 256, 0, stream>>>(w5, w10, w15, gw, mw, cBg, gBg, stats);
    k_pool<<<BN * 8, 256, 0, stream>>>(x, p5i, p10i, p15i);
    dim3 grid(GX, GY, BN);
    k_fused<<<grid, 256, 0, stream>>>(x, p5i, p10i, p15i,
                                      (const unsigned short*)cBg, (const unsigned short*)gBg,
                                      b5, b10, b15, gb, mb, out, stats);
    k_stats<<<1, 64, 0, stream>>>(stats, gamma, beta, ss);
    k_norm<<<(BN * 8 * HW / 4 + 255) / 256, 256, 0, stream>>>(out, ss);
}

// Round 7
// 417.790 us; speedup vs baseline: 2.5522x; 1.0219x over previous
//
#include <hip/hip_runtime.h>
#include <math.h>

typedef __bf16 bfrag __attribute__((ext_vector_type(8)));
typedef float f32x4 __attribute__((ext_vector_type(4)));

// Problem constants
#define BN 32
#define HH 300
#define WW 300
#define HW 90000
#define NPX (BN * HW)

// Output tile 16 rows x 32 cols
#define GX 10   // ceil(300/32)
#define GY 19   // ceil(300/16)

// Workspace layout (bytes)
#define P5I_BYTE_OFF   0         // [32][3600][8] bf16 = 1,843,200
#define P10I_BYTE_OFF  1843200   // [32][900][8]  bf16 = 460,800
#define P15I_BYTE_OFF  2304000   // [32][400][8]  bf16 = 204,800
#define CWB_BYTE_OFF   2508800   // [3][16][10][16] bf16 = 15,360
#define GWB_BYTE_OFF   2524160   // [16][28][8] bf16 = 7,168
#define STAT_BYTE_OFF  2531328   // [16][64] doubles = 8,192
#define SS_BYTE_OFF    2539520   // 16 floats

__device__ __forceinline__ short f2bf(float f) {
    union { float f; unsigned u; } v;
    v.f = f;
    unsigned r = v.u + 0x7FFF + ((v.u >> 16) & 1);
    return (short)(r >> 16);
}

__device__ __forceinline__ float bf2f(unsigned short s) {
    union { unsigned u; float f; } v;
    v.u = ((unsigned)s) << 16;
    return v.f;
}

// ---------------------------------------------------------------------------
// K0: build bf16 MFMA weight layouts + zero BN stat bins
// cB[s][n16][tap10][ci16]  (n>=8, tap==9 -> 0);  gB[n16][blk28][cj8] (blk>=27 -> 0)
// ---------------------------------------------------------------------------
__global__ void k_setup(const float* __restrict__ w5, const float* __restrict__ w10,
                        const float* __restrict__ w15, const float* __restrict__ gw,
                        const float* __restrict__ mw, short* __restrict__ cBg,
                        short* __restrict__ gBg, double* __restrict__ stats) {
    int t = threadIdx.x;
    for (int idx = t; idx < 7680; idx += 256) {
        int s = idx / 2560, rem = idx % 2560;
        int n = rem / 160, r2 = rem % 160;
        int tap = r2 / 16, ci = r2 % 16;
        float v = 0.f;
        if (n < 8 && tap < 9) {
            const float* W = (s == 0) ? w5 : ((s == 1) ? w10 : w15);
            v = W[(n * 16 + ci) * 9 + tap];
        }
        cBg[idx] = f2bf(v);
    }
    for (int idx = t; idx < 3584; idx += 256) {
        int n = idx / 224, r2 = idx % 224;
        int blk = r2 / 8, cj = r2 % 8;
        float v = 0.f;
        if (blk < 27) {
            int tap = blk / 3, ci24 = (blk % 3) * 8 + cj;
            if (n < 8) v = gw[(n * 24 + ci24) * 9 + tap];
            else       v = mw[((n - 8) * 24 + ci24) * 9 + tap];
        }
        gBg[idx] = f2bf(v);
    }
    for (int idx = t; idx < 16 * 64; idx += 256) stats[idx] = 0.0;
}

// ---------------------------------------------------------------------------
// K1a: 5x5 pool, one thread per (b, cell, ch). 3600 blocks — BW-bound.
// id = bc*3600 + cell  (pj fastest -> stride-5 reads, full line use via v-loop)
// ---------------------------------------------------------------------------
__global__ void k_pool5(const float* __restrict__ x, unsigned short* __restrict__ p5i) {
    int id = blockIdx.x * 256 + threadIdx.x;  // < 921600
    int bc = id / 3600, cell = id % 3600;
    int b = bc >> 3, c = bc & 7;
    int pi = cell / 60, pj = cell % 60;
    const float* rp = x + (size_t)bc * HW + pi * 5 * WW + pj * 5;
    float s = 0.f;
#pragma unroll
    for (int u = 0; u < 5; u++)
#pragma unroll
        for (int v = 0; v < 5; v++) s += rp[u * WW + v];
    p5i[((size_t)b * 3600 + cell) * 8 + c] = (unsigned short)f2bf(s * 0.04f);
}

// ---------------------------------------------------------------------------
// K1b: derive 10x10 and 15x15 pools from p5i (L2-hot, tiny)
// ---------------------------------------------------------------------------
__global__ void k_poolD(const unsigned short* __restrict__ p5i,
                        unsigned short* __restrict__ p10i,
                        unsigned short* __restrict__ p15i) {
    int id = blockIdx.x * 256 + threadIdx.x;
    if (id < 230400) {  // p10: (b,ch) x 900 cells
        int bc = id / 900, cell = id % 900;
        int b = bc >> 3, c = bc & 7;
        int pi = cell / 30, pj = cell % 30;
        const unsigned short* base = p5i + ((size_t)b * 3600) * 8 + c;
        float s = bf2f(base[((2 * pi) * 60 + 2 * pj) * 8]) +
                  bf2f(base[((2 * pi) * 60 + 2 * pj + 1) * 8]) +
                  bf2f(base[((2 * pi + 1) * 60 + 2 * pj) * 8]) +
                  bf2f(base[((2 * pi + 1) * 60 + 2 * pj + 1) * 8]);
        p10i[((size_t)b * 900 + cell) * 8 + c] = (unsigned short)f2bf(s * 0.25f);
    } else if (id < 332800) {  // p15: (b,ch) x 400 cells
        int id2 = id - 230400;
        int bc = id2 / 400, cell = id2 % 400;
        int b = bc >> 3, c = bc & 7;
        int pi = cell / 20, pj = cell % 20;
        const unsigned short* base = p5i + ((size_t)b * 3600) * 8 + c;
        float s = 0.f;
#pragma unroll
        for (int u = 0; u < 3; u++)
#pragma unroll
            for (int v = 0; v < 3; v++)
                s += bf2f(base[((3 * pi + u) * 60 + 3 * pj + v) * 8]);
        p15i[((size_t)b * 400 + cell) * 8 + c] = (unsigned short)f2bf(s * (1.f / 9.f));
    }
}

// ---------------------------------------------------------------------------
// up-channel staging, software-pipelined: global 16B load of interleaved
// pooled cell -> registers (issued before the barrier), LDS write after.
// ---------------------------------------------------------------------------
template <int K, int PW>
__device__ __forceinline__ void up_load(const unsigned short* __restrict__ pooled,
                                        int b, int r0, int c0, int t, uint4* v) {
#pragma unroll
    for (int it = 0; it < 3; it++) {
        int idx = t + 256 * it;
        uint4 val = {0u, 0u, 0u, 0u};
        if (idx < 720) {
            int i = idx / 36, j = idx - i * 36;
            int ra = r0 - 2 + i, ca = c0 - 2 + j;
            if (ra >= 0 && ra < HH && ca >= 0 && ca < WW) {
                int pi = (int)((unsigned)ra / K);
                int pj = (int)((unsigned)ca / K);
                val = *(const uint4*)&pooled[((size_t)b * (PW * PW) + pi * PW + pj) * 8];
            }
        }
        v[it] = val;
    }
}

__device__ __forceinline__ void up_store(short* xu, int t, const uint4* v) {
#pragma unroll
    for (int it = 0; it < 3; it++) {
        int idx = t + 256 * it;
        if (idx < 720) *(uint4*)&xu[idx * 16 + 8] = v[it];
    }
}

// ---------------------------------------------------------------------------
// c-phase: conv([x, up_s]) over the 18x34 c-tile via 39 M-groups x 5 K-MFMAs
// weight index (tapw) UNCLAMPED (pad slot multiplies genuine zeros); only the
// A-side address (tapa) is clamped as an OOB guard. B-fragments from global.
// Epilogue: one magic-div per group, then incremental c2 wrap.
// ---------------------------------------------------------------------------
__device__ __forceinline__ void c_phase(const short* xu, short* cwS,
                                        const unsigned short* __restrict__ cBs,
                                        const float* __restrict__ bias, int s,
                                        int r0, int c0, int lane, int wid) {
    const int n = lane & 15, quad = lane >> 4;
    const int qh = quad >> 1, ql = quad & 1;
    bfrag bfr[5];
    int tapoff[5];
#pragma unroll
    for (int km = 0; km < 5; km++) {
        int tapw = km * 2 + qh;                 // 9 -> zero row in cB
        int tapa = (tapw > 8) ? 8 : tapw;       // address clamp only
        bfr[km] = *(const bfrag*)&cBs[(n * 10 + tapw) * 16 + ql * 8];
        tapoff[km] = ((tapa / 3) * 36 + tapa % 3) * 16;
    }
    float bo = (n < 8) ? bias[n] : 0.f;
    for (int g = wid; g < 39; g += 4) {
        int px = g * 16 + n;
        if (px > 611) px = 611;
        int rp = px / 34, cp = px - rp * 34;
        int off0 = (rp * 36 + cp) * 16 + ql * 8;
        f32x4 acc = {0.f, 0.f, 0.f, 0.f};
#pragma unroll
        for (int km = 0; km < 5; km++)
            acc = __builtin_amdgcn_mfma_f32_16x16x32_bf16(
                *(const bfrag*)&xu[off0 + tapoff[km]], bfr[km], acc, 0, 0, 0);
        if (n < 8) {
            int px2 = g * 16 + quad * 4;
            int r2 = px2 / 34, c2 = px2 - r2 * 34;
#pragma unroll
            for (int reg = 0; reg < 4; reg++) {
                if (px2 + reg < 612) {
                    int ra = r0 - 1 + r2, ca = c0 - 1 + c2;
                    float v = acc[reg] + bo;
                    if (ra < 0 || ra >= HH || ca < 0 || ca >= WW) v = 0.f;
                    cwS[(r2 * 34 + c2) * 24 + s * 8 + n] = f2bf(v);
                }
                c2++;
                if (c2 == 34) { c2 = 0; r2++; }
            }
        }
    }
}

// ---------------------------------------------------------------------------
// K2: fused MFMA kernel — one 16x32 output tile per 256-thread block
// LDS = xu(23040B) + cwS(29376B) = 52.4KB -> 3 blocks/CU
// ---------------------------------------------------------------------------
__global__ __launch_bounds__(256, 3) void k_fused(
    const float* __restrict__ x,
    const unsigned short* __restrict__ p5i, const unsigned short* __restrict__ p10i,
    const unsigned short* __restrict__ p15i,
    const unsigned short* __restrict__ cBg, const unsigned short* __restrict__ gBg,
    const float* __restrict__ b5, const float* __restrict__ b10, const float* __restrict__ b15,
    const float* __restrict__ gb, const float* __restrict__ mb,
    float* __restrict__ out, double* __restrict__ stats) {
    __shared__ __align__(16) short xu[20 * 36 * 16];   // [i20][j36][ci16] (x:0-7, up:8-15)
    __shared__ __align__(16) short cwS[18 * 34 * 24];  // [r18][c34][ci24]

    const int b = blockIdx.z;
    const int r0 = blockIdx.y * 16, c0 = blockIdx.x * 32;
    const int t = threadIdx.x, lane = t & 63, wid = t >> 6;

    // pipeline scale-0 pooled loads early (global->reg, no LDS dep)
    uint4 upv[3];
    up_load<5, 60>(p5i, b, r0, c0, t, upv);

    // x half of xu: pixel-pair staging (ca always even -> one bounds check,
    // two aligned float2 loads per pair)
    for (int idx = t; idx < 1440; idx += 256) {
        int cp = idx / 360, rem = idx % 360;
        int i = rem / 18, jp = rem % 18;
        int j = 2 * jp;
        int ra = r0 - 2 + i, ca = c0 - 2 + j;
        float2 v0 = {0.f, 0.f}, v1 = {0.f, 0.f};
        if (ra >= 0 && ra < HH && ca >= 0 && ca <= WW - 2) {
            size_t base = ((size_t)(b * 8 + 2 * cp) * HH + ra) * WW + ca;
            v0 = *(const float2*)&x[base];
            v1 = *(const float2*)&x[base + HW];
        }
        unsigned pA = (unsigned short)f2bf(v0.x) | ((unsigned)(unsigned short)f2bf(v1.x) << 16);
        unsigned pB = (unsigned short)f2bf(v0.y) | ((unsigned)(unsigned short)f2bf(v1.y) << 16);
        int px = i * 36 + j;
        *(unsigned*)&xu[px * 16 + 2 * cp] = pA;
        *(unsigned*)&xu[(px + 1) * 16 + 2 * cp] = pB;
    }
    up_store(xu, t, upv);
    __syncthreads();

    c_phase(xu, cwS, cBg, b5, 0, r0, c0, lane, wid);
    up_load<10, 30>(p10i, b, r0, c0, t, upv);   // overlaps c_phase compute
    __syncthreads();
    up_store(xu, t, upv);
    __syncthreads();

    c_phase(xu, cwS, cBg + 2560, b10, 1, r0, c0, lane, wid);
    up_load<15, 20>(p15i, b, r0, c0, t, upv);
    __syncthreads();
    up_store(xu, t, upv);
    __syncthreads();

    c_phase(xu, cwS, cBg + 5120, b15, 2, r0, c0, lane, wid);
    __syncthreads();

    // gate phase: N=16 packs G(0-7) and M(8-15); 32 M-groups x 7 K-MFMAs
    const int n = lane & 15, quad = lane >> 4;
    bfrag gfr[7];
    int goff[7];
#pragma unroll
    for (int km = 0; km < 7; km++) {
        int blkw = km * 4 + quad;               // 27 -> zero block in gB
        int blka = (blkw > 26) ? 26 : blkw;     // address clamp only
        gfr[km] = *(const bfrag*)&gBg[(n * 28 + blkw) * 8];
        int tap = blka / 3, cig = blka - tap * 3;
        goff[km] = ((tap / 3) * 34 + tap % 3) * 24 + cig * 8;
    }
    float gbv = (n < 8) ? gb[n] : 0.f;
    float mbv = (n < 8) ? mb[n] : 0.f;
    float ls = 0.f, ls2 = 0.f;

    for (int g = wid; g < 32; g += 4) {
        int px = g * 16 + n;
        int rr = px >> 5, cc2 = px & 31;
        int off0 = (rr * 34 + cc2) * 24;
        f32x4 acc = {0.f, 0.f, 0.f, 0.f};
#pragma unroll
        for (int km = 0; km < 7; km++)
            acc = __builtin_amdgcn_mfma_f32_16x16x32_bf16(
                *(const bfrag*)&cwS[off0 + goff[km]], gfr[km], acc, 0, 0, 0);
#pragma unroll
        for (int reg = 0; reg < 4; reg++) {
            float other = __shfl_xor(acc[reg], 8);  // pair G (n<8) with M (n+8)
            if (n < 8) {
                int px2 = g * 16 + quad * 4 + reg;
                int rr2 = px2 >> 5, cc3 = px2 & 31;
                int ra = r0 + rr2, ca = c0 + cc3;
                if (ra < HH && ca < WW) {
                    float G = acc[reg] + gbv, M = other + mbv;
                    float y = G / (1.f + __expf(-M));
                    out[((size_t)(b * 8 + n) * HH + ra) * WW + ca] = y;
                    ls += y;
                    ls2 += y * y;
                }
            }
        }
    }
    // BN partials: quad-fold via shfl_xor, then hashed-bin double atomics
    ls += __shfl_xor(ls, 16);
    ls += __shfl_xor(ls, 32);
    ls2 += __shfl_xor(ls2, 16);
    ls2 += __shfl_xor(ls2, 32);
    if (lane < 8) {
        int hash = (blockIdx.x + GX * blockIdx.y + GX * GY * blockIdx.z) & 63;
        atomicAdd(&stats[lane * 64 + hash], (double)ls);
        atomicAdd(&stats[(8 + lane) * 64 + hash], (double)ls2);
    }
}

// ---------------------------------------------------------------------------
__global__ void k_stats(const double* __restrict__ stats, const float* __restrict__ gamma,
                        const float* __restrict__ beta, float* __restrict__ ss) {
    __shared__ double tot[16];
    int t = threadIdx.x;
    if (t < 16) {
        double s = 0.0;
        for (int i = 0; i < 64; i++) s += stats[t * 64 + i];
        tot[t] = s;
    }
    __syncthreads();
    if (t < 8) {
        double N = (double)NPX;
        double mean = tot[t] / N;
        double var = tot[8 + t] / N - mean * mean;
        double scale = (double)gamma[t] / sqrt(var + 1e-5);
        ss[t] = (float)scale;
        ss[8 + t] = (float)((double)beta[t] - mean * scale);
    }
}

// ---------------------------------------------------------------------------
__global__ void k_norm(float* __restrict__ out, const float* __restrict__ ss) {
    int i = blockIdx.x * 256 + threadIdx.x;
    if (i < (BN * 8 * HW) / 4) {
        int plane = (i * 4) / HW;
        int ch = plane & 7;
        float sc = ss[ch], sh = ss[8 + ch];
        float4* p = (float4*)out + i;
        float4 v = *p;
        v.x = v.x * sc + sh;
        v.y = v.y * sc + sh;
        v.z = v.z * sc + sh;
        v.w = v.w * sc + sh;
        *p = v;
    }
}

// ---------------------------------------------------------------------------
extern "C" void kernel_launch(void* const* d_in, const int* in_sizes, int n_in,
                              void* d_out, int out_size, void* d_ws, size_t ws_size,
                              hipStream_t stream) {
    const float* x = (const float*)d_in[0];
    const float* w5 = (const float*)d_in[1];
    const float* b5 = (const float*)d_in[2];
    const float* w10 = (const float*)d_in[3];
    const float* b10 = (const float*)d_in[4];
    const float* w15 = (const float*)d_in[5];
    const float* b15 = (const float*)d_in[6];
    const float* gw = (const float*)d_in[7];
    const float* gb = (const float*)d_in[8];
    const float* mw = (const float*)d_in[9];
    const float* mb = (const float*)d_in[10];
    const float* gamma = (const float*)d_in[11];
    const float* beta = (const float*)d_in[12];

    float* out = (float*)d_out;
    unsigned short* p5i = (unsigned short*)((char*)d_ws + P5I_BYTE_OFF);
    unsigned short* p10i = (unsigned short*)((char*)d_ws + P10I_BYTE_OFF);
    unsigned short* p15i = (unsigned short*)((char*)d_ws + P15I_BYTE_OFF);
    short* cBg = (short*)((char*)d_ws + CWB_BYTE_OFF);
    short* gBg = (short*)((char*)d_ws + GWB_BYTE_OFF);
    double* stats = (double*)((char*)d_ws + STAT_BYTE_OFF);
    float* ss = (float*)((char*)d_ws + SS_BYTE_OFF);

    k_setup<<<1, 256, 0, stream>>>(w5, w10, w15, gw, mw, cBg, gBg, stats);
    k_pool5<<<3600, 256, 0, stream>>>(x, p5i);
    k_poolD<<<1300, 256, 0, stream>>>(p5i, p10i, p15i);
    dim3 grid(GX, GY, BN);
    k_fused<<<grid, 256, 0, stream>>>(x, p5i, p10i, p15i,
                                      (const unsigned short*)cBg, (const unsigned short*)gBg,
                                      b5, b10, b15, gb, mb, out, stats);
    k_stats<<<1, 64, 0, stream>>>(stats, gamma, beta, ss);
    k_norm<<<(BN * 8 * HW / 4 + 255) / 256, 256, 0, stream>>>(out, ss);
}